// Round 10
// baseline (382.252 us; speedup 1.0000x reference)
//
#include <hip/hip_runtime.h>
#include <hip/hip_cooperative_groups.h>
#include <math.h>

namespace cg = cooperative_groups;

#define N_NODES 40000
#define D 128
#define NEDGE 640000
#define CAP 80              // fixed per-node entry capacity; Poisson(32), max ~58 observed
#define NGROUP (N_NODES / 8)

__device__ __forceinline__ unsigned short bf16rn(float f) {
    unsigned u = __float_as_uint(f);
    unsigned r = u + 0x7FFFu + ((u >> 16) & 1u);
    return (unsigned short)(r >> 16);
}

// ---------------- single cooperative mega-kernel: init | expand | gather+linear ---------
template <int USE_BF16>
__global__ __launch_bounds__(256) void mega_kernel(
    const float* __restrict__ x, unsigned short* __restrict__ xb,
    const int* __restrict__ row, const int* __restrict__ col,
    int* __restrict__ cursor, unsigned* __restrict__ entries,
    const float* __restrict__ W1, const float* __restrict__ b1,
    const float* __restrict__ W2, const float* __restrict__ b2,
    float* __restrict__ Wc, float* __restrict__ bc,
    float* __restrict__ out) {
    cg::grid_group grid = cg::this_grid();
    int gtid = blockIdx.x * blockDim.x + threadIdx.x;
    int gstride = gridDim.x * blockDim.x;

    // ---- Phase A: init cursors, fold linear weights, optional bf16 cast of x ----
    for (int t = gtid; t < N_NODES; t += gstride) cursor[t] = 0;
    for (int t = gtid; t < D * D; t += gstride) Wc[t] = 0.5f * (W1[t] + W2[t]);
    for (int t = gtid; t < D; t += gstride) bc[t] = 0.5f * (b1[t] + b2[t]);
    if (USE_BF16) {
        for (int t = gtid; t < N_NODES * D / 4; t += gstride) {
            float4 v = ((const float4*)x)[t];
            ushort4 o;
            o.x = bf16rn(v.x); o.y = bf16rn(v.y); o.z = bf16rn(v.z); o.w = bf16rn(v.w);
            ((ushort4*)xb)[t] = o;
        }
    }
    grid.sync();

    // ---- Phase B: expand edges into fixed-capacity per-node segments ----
    // (r,c) -> (c | dir0) into r's segment, (r | dir1) into c's segment. Rev-edge
    // detection is segment-local later: edge (c,r) would place (c | dir1) in r's segment.
    for (int e = gtid; e < NEDGE; e += gstride) {
        int r = row[e], c = col[e];
        int p1 = atomicAdd(&cursor[r], 1);
        if (p1 < CAP) entries[(size_t)r * CAP + p1] = (unsigned)c;              // dir = 0
        int p2 = atomicAdd(&cursor[c], 1);
        if (p2 < CAP) entries[(size_t)c * CAP + p2] = (unsigned)r | 0x10000u;   // dir = 1
    }
    grid.sync();

    // ---- Phase C: fused gather + linear (r9 shape), grid-strided over node groups ----
    __shared__ unsigned rawlds[4][2][CAP];   // 2560 B
    __shared__ uint4 slds[4][2][CAP];        // 10240 B : src, sre, sim, pad
    __shared__ float ylds[8][260];           // 8320 B, padded stride

    int tid = threadIdx.x;
    int wave = tid >> 6, half = (tid >> 5) & 1, l = tid & 31;
    int n = wave * 2 + half;

    for (int g = blockIdx.x; g < NGROUP; g += gridDim.x) {
        __syncthreads();                     // protect ylds/slds reuse across iterations
        int u = g * 8 + n;

        int cnt = cursor[u];
        int m = min(cnt, CAP);
        float dinv_u = (cnt > 0) ? rsqrtf(0.5f * (float)cnt) : 0.f;
        const unsigned* eb = entries + (size_t)u * CAP;

        for (int idx = l; idx < m; idx += 32) rawlds[wave][half][idx] = eb[idx];
        __builtin_amdgcn_wave_barrier();

        for (int idx = l; idx < m; idx += 32) {
            unsigned e = rawlds[wave][half][idx];
            unsigned src = e & 0xFFFFu;
            unsigned dir = (e >> 16) & 1u;
            unsigned tgt = e ^ 0x10000u;     // same src, opposite dir
            bool rev = false;
            for (int j = 0; j < m; ++j)
                rev |= (rawlds[wave][half][j] == tgt);
            int cs = cursor[src];
            float s = 0.5f * dinv_u * rsqrtf(0.5f * (float)max(cs, 1));
            float sre = 0.f, sim = 0.f;
            if (rev) sre = s;
            else sim = dir ? -s : s;
            slds[wave][half][idx] = make_uint4(src, __float_as_uint(sre),
                                               __float_as_uint(sim), 0u);
        }
        __builtin_amdgcn_wave_barrier();

        float4 accre = make_float4(0.f, 0.f, 0.f, 0.f);
        float4 accim = make_float4(0.f, 0.f, 0.f, 0.f);

        if (USE_BF16) {
            #pragma unroll 8
            for (int i = 0; i < m; ++i) {
                uint4 t = slds[wave][half][i];
                uint2 v = ((const uint2*)(xb + (size_t)t.x * D))[l];
                float fre = __uint_as_float(t.y), fim = __uint_as_float(t.z);
                float v0 = __uint_as_float(v.x << 16);
                float v1 = __uint_as_float(v.x & 0xFFFF0000u);
                float v2 = __uint_as_float(v.y << 16);
                float v3 = __uint_as_float(v.y & 0xFFFF0000u);
                accre.x += fre * v0; accre.y += fre * v1;
                accre.z += fre * v2; accre.w += fre * v3;
                accim.x += fim * v0; accim.y += fim * v1;
                accim.z += fim * v2; accim.w += fim * v3;
            }
        } else {
            #pragma unroll 4
            for (int i = 0; i < m; ++i) {
                uint4 t = slds[wave][half][i];
                float4 v = ((const float4*)(x + (size_t)t.x * D))[l];
                float fre = __uint_as_float(t.y), fim = __uint_as_float(t.z);
                accre.x += fre * v.x; accre.y += fre * v.y;
                accre.z += fre * v.z; accre.w += fre * v.w;
                accim.x += fim * v.x; accim.y += fim * v.y;
                accim.z += fim * v.z; accim.w += fim * v.w;
            }
        }

        *(float4*)&ylds[n][l * 4] = accre;
        *(float4*)&ylds[n][128 + l * 4] = accim;
        __syncthreads();

        int n2 = tid >> 5, c = tid & 31;
        int u2 = g * 8 + n2;
        const float* yb = &ylds[n2][0];
        const float4* Wc4 = (const float4*)Wc;
        float4 ar = make_float4(0.f, 0.f, 0.f, 0.f);
        float4 ai = make_float4(0.f, 0.f, 0.f, 0.f);
        #pragma unroll 4
        for (int k = 0; k < 128; k += 4) {
            float4 yr4 = *(const float4*)&yb[k];
            float4 yi4 = *(const float4*)&yb[128 + k];
            #pragma unroll
            for (int j = 0; j < 4; ++j) {
                float4 w = Wc4[(k + j) * 32 + c];
                float yr = (j == 0) ? yr4.x : (j == 1) ? yr4.y : (j == 2) ? yr4.z : yr4.w;
                float yi = (j == 0) ? yi4.x : (j == 1) ? yi4.y : (j == 2) ? yi4.z : yi4.w;
                ar.x += yr * w.x; ar.y += yr * w.y; ar.z += yr * w.z; ar.w += yr * w.w;
                ai.x += yi * w.x; ai.y += yi * w.y; ai.z += yi * w.z; ai.w += yi * w.w;
            }
        }
        float4 bv = ((const float4*)bc)[c];
        ar.x += bv.x; ar.y += bv.y; ar.z += bv.z; ar.w += bv.w;
        ai.x += bv.x; ai.y += bv.y; ai.z += bv.z; ai.w += bv.w;
        *(float4*)&out[(size_t)u2 * 256 + c * 4] = ar;
        *(float4*)&out[(size_t)u2 * 256 + 128 + c * 4] = ai;
    }
}

// ---------------- r9 fallback kernels (used only if cooperative launch fails) ----------
__global__ void init_kernel(int* __restrict__ cursor,
                            const float* __restrict__ W1, const float* __restrict__ b1,
                            const float* __restrict__ W2, const float* __restrict__ b2,
                            float* __restrict__ Wc, float* __restrict__ bc,
                            const float* __restrict__ x, unsigned short* __restrict__ xb) {
    int i = blockIdx.x * blockDim.x + threadIdx.x;
    int stride = gridDim.x * blockDim.x;
    for (int t = i; t < N_NODES; t += stride) cursor[t] = 0;
    for (int t = i; t < D * D; t += stride) Wc[t] = 0.5f * (W1[t] + W2[t]);
    if (i < D) bc[i] = 0.5f * (b1[i] + b2[i]);
    if (xb) {
        for (int t = i; t < N_NODES * D / 4; t += stride) {
            float4 v = ((const float4*)x)[t];
            ushort4 o;
            o.x = bf16rn(v.x); o.y = bf16rn(v.y); o.z = bf16rn(v.z); o.w = bf16rn(v.w);
            ((ushort4*)xb)[t] = o;
        }
    }
}

__global__ void expand_kernel(const int* __restrict__ row, const int* __restrict__ col,
                              int* __restrict__ cursor, unsigned* __restrict__ entries) {
    int e = blockIdx.x * blockDim.x + threadIdx.x;
    if (e >= NEDGE) return;
    int r = row[e], c = col[e];
    int p1 = atomicAdd(&cursor[r], 1);
    if (p1 < CAP) entries[(size_t)r * CAP + p1] = (unsigned)c;
    int p2 = atomicAdd(&cursor[c], 1);
    if (p2 < CAP) entries[(size_t)c * CAP + p2] = (unsigned)r | 0x10000u;
}

template <int USE_BF16>
__global__ __launch_bounds__(256) void fused_kernel(
    const float* __restrict__ x, const unsigned short* __restrict__ xb,
    const unsigned* __restrict__ entries, const int* __restrict__ cursor,
    const float* __restrict__ Wc, const float* __restrict__ bc,
    float* __restrict__ out) {
    __shared__ unsigned rawlds[4][2][CAP];
    __shared__ uint4 slds[4][2][CAP];
    __shared__ float ylds[8][260];

    int tid = threadIdx.x;
    int wave = tid >> 6, half = (tid >> 5) & 1, l = tid & 31;
    int n = wave * 2 + half;
    int u = blockIdx.x * 8 + n;

    int cnt = cursor[u];
    int m = min(cnt, CAP);
    float dinv_u = (cnt > 0) ? rsqrtf(0.5f * (float)cnt) : 0.f;
    const unsigned* eb = entries + (size_t)u * CAP;

    for (int idx = l; idx < m; idx += 32) rawlds[wave][half][idx] = eb[idx];
    __builtin_amdgcn_wave_barrier();

    for (int idx = l; idx < m; idx += 32) {
        unsigned e = rawlds[wave][half][idx];
        unsigned src = e & 0xFFFFu;
        unsigned dir = (e >> 16) & 1u;
        unsigned tgt = e ^ 0x10000u;
        bool rev = false;
        for (int j = 0; j < m; ++j)
            rev |= (rawlds[wave][half][j] == tgt);
        int cs = cursor[src];
        float s = 0.5f * dinv_u * rsqrtf(0.5f * (float)max(cs, 1));
        float sre = 0.f, sim = 0.f;
        if (rev) sre = s;
        else sim = dir ? -s : s;
        slds[wave][half][idx] = make_uint4(src, __float_as_uint(sre),
                                           __float_as_uint(sim), 0u);
    }
    __builtin_amdgcn_wave_barrier();

    float4 accre = make_float4(0.f, 0.f, 0.f, 0.f);
    float4 accim = make_float4(0.f, 0.f, 0.f, 0.f);

    if (USE_BF16) {
        #pragma unroll 8
        for (int i = 0; i < m; ++i) {
            uint4 t = slds[wave][half][i];
            uint2 v = ((const uint2*)(xb + (size_t)t.x * D))[l];
            float fre = __uint_as_float(t.y), fim = __uint_as_float(t.z);
            float v0 = __uint_as_float(v.x << 16);
            float v1 = __uint_as_float(v.x & 0xFFFF0000u);
            float v2 = __uint_as_float(v.y << 16);
            float v3 = __uint_as_float(v.y & 0xFFFF0000u);
            accre.x += fre * v0; accre.y += fre * v1;
            accre.z += fre * v2; accre.w += fre * v3;
            accim.x += fim * v0; accim.y += fim * v1;
            accim.z += fim * v2; accim.w += fim * v3;
        }
    } else {
        #pragma unroll 4
        for (int i = 0; i < m; ++i) {
            uint4 t = slds[wave][half][i];
            float4 v = ((const float4*)(x + (size_t)t.x * D))[l];
            float fre = __uint_as_float(t.y), fim = __uint_as_float(t.z);
            accre.x += fre * v.x; accre.y += fre * v.y;
            accre.z += fre * v.z; accre.w += fre * v.w;
            accim.x += fim * v.x; accim.y += fim * v.y;
            accim.z += fim * v.z; accim.w += fim * v.w;
        }
    }

    *(float4*)&ylds[n][l * 4] = accre;
    *(float4*)&ylds[n][128 + l * 4] = accim;
    __syncthreads();

    int n2 = tid >> 5, c = tid & 31;
    int u2 = blockIdx.x * 8 + n2;
    const float* yb = &ylds[n2][0];
    const float4* Wc4 = (const float4*)Wc;
    float4 ar = make_float4(0.f, 0.f, 0.f, 0.f);
    float4 ai = make_float4(0.f, 0.f, 0.f, 0.f);
    #pragma unroll 4
    for (int k = 0; k < 128; k += 4) {
        float4 yr4 = *(const float4*)&yb[k];
        float4 yi4 = *(const float4*)&yb[128 + k];
        #pragma unroll
        for (int j = 0; j < 4; ++j) {
            float4 w = Wc4[(k + j) * 32 + c];
            float yr = (j == 0) ? yr4.x : (j == 1) ? yr4.y : (j == 2) ? yr4.z : yr4.w;
            float yi = (j == 0) ? yi4.x : (j == 1) ? yi4.y : (j == 2) ? yi4.z : yi4.w;
            ar.x += yr * w.x; ar.y += yr * w.y; ar.z += yr * w.z; ar.w += yr * w.w;
            ai.x += yi * w.x; ai.y += yi * w.y; ai.z += yi * w.z; ai.w += yi * w.w;
        }
    }
    float4 bv = ((const float4*)bc)[c];
    ar.x += bv.x; ar.y += bv.y; ar.z += bv.z; ar.w += bv.w;
    ai.x += bv.x; ai.y += bv.y; ai.z += bv.z; ai.w += bv.w;
    *(float4*)&out[(size_t)u2 * 256 + c * 4] = ar;
    *(float4*)&out[(size_t)u2 * 256 + 128 + c * 4] = ai;
}

extern "C" void kernel_launch(void* const* d_in, const int* in_sizes, int n_in,
                              void* d_out, int out_size, void* d_ws, size_t ws_size,
                              hipStream_t stream) {
    const float* x  = (const float*)d_in[0];
    const int*   ei = (const int*)d_in[1];
    const float* W1 = (const float*)d_in[2];
    const float* b1 = (const float*)d_in[3];
    const float* W2 = (const float*)d_in[4];
    const float* b2 = (const float*)d_in[5];
    float* out = (float*)d_out;
    const int* row = ei;
    const int* col = ei + NEDGE;

    char* ws = (char*)d_ws;
    float*    Wc      = (float*)ws;                    // 0        .. 65536
    float*    bc      = (float*)(ws + 65536);          // 65536    .. 66048
    int*      cursor  = (int*)(ws + 66048);            // 66048    .. 226048
    unsigned* entries = (unsigned*)(ws + 226048);      // 226048   .. 13026048 (N*CAP*4)
    const size_t xoff = 13026048;
    const size_t XBB = (size_t)N_NODES * D * 2;        // 10.24 MB

    unsigned short* xb = nullptr;
    bool bf16 = false;
    if (ws_size >= xoff + XBB) {
        xb = (unsigned short*)(ws + xoff);
        bf16 = true;
    }

    const void* fn = bf16 ? reinterpret_cast<const void*>(&mega_kernel<1>)
                          : reinterpret_cast<const void*>(&mega_kernel<0>);
    int nb = 0;
    if (hipOccupancyMaxActiveBlocksPerMultiprocessor(&nb, fn, 256, 0) != hipSuccess || nb <= 0)
        nb = 4;                                        // conservative: 4 x 21.5KB LDS fits
    int grid = nb * 256;                               // 256 CUs on MI355X
    if (grid > 2048) grid = 2048;

    void* args[] = {(void*)&x, (void*)&xb, (void*)&row, (void*)&col,
                    (void*)&cursor, (void*)&entries,
                    (void*)&W1, (void*)&b1, (void*)&W2, (void*)&b2,
                    (void*)&Wc, (void*)&bc, (void*)&out};
    hipError_t err = hipLaunchCooperativeKernel(fn, dim3(grid), dim3(256), args, 0, stream);

    if (err != hipSuccess) {
        // Fallback: proven r9 3-kernel path.
        init_kernel<<<2048, 256, 0, stream>>>(cursor, W1, b1, W2, b2, Wc, bc, x, xb);
        expand_kernel<<<(NEDGE + 255) / 256, 256, 0, stream>>>(row, col, cursor, entries);
        if (bf16) {
            fused_kernel<1><<<N_NODES / 8, 256, 0, stream>>>(x, xb, entries, cursor,
                                                             Wc, bc, out);
        } else {
            fused_kernel<0><<<N_NODES / 8, 256, 0, stream>>>(x, xb, entries, cursor,
                                                             Wc, bc, out);
        }
    }
}

// Round 11
// 196.292 us; speedup vs baseline: 1.9474x; 1.9474x over previous
//
#include <hip/hip_runtime.h>
#include <math.h>

#define N_NODES 40000
#define D 128
#define NEDGE 640000
#define CAP 80              // fixed per-node entry capacity; in+out deg Poisson(32), max ~58

__device__ __forceinline__ unsigned short bf16rn(float f) {
    unsigned u = __float_as_uint(f);
    unsigned r = u + 0x7FFFu + ((u >> 16) & 1u);
    return (unsigned short)(r >> 16);
}

// Tiny: clear the two cursor arrays; fold Wc = 0.5*(W1+W2), bc = 0.5*(b1+b2).
__global__ void init_kernel(int* __restrict__ cursorA, int* __restrict__ cursorB,
                            const float* __restrict__ W1, const float* __restrict__ b1,
                            const float* __restrict__ W2, const float* __restrict__ b2,
                            float* __restrict__ Wc, float* __restrict__ bc) {
    int i = blockIdx.x * blockDim.x + threadIdx.x;
    int stride = gridDim.x * blockDim.x;
    for (int t = i; t < N_NODES; t += stride) { cursorA[t] = 0; cursorB[t] = 0; }
    for (int t = i; t < D * D; t += stride) Wc[t] = 0.5f * (W1[t] + W2[t]);
    if (i < D) bc[i] = 0.5f * (b1[i] + b2[i]);
}

// Edge (r,c): src c goes into r's segment bottom-up (dir0 = out-edge of r),
// src r goes into c's segment top-down (dir1 = in-edge of c). Direction is encoded
// by POSITION, so entries are bare 16-bit src ids. Rev-edge detection is segment-local
// in fused: (r,c) has a reverse iff r's dir1 region also contains src c.
// The bf16 cast of x rides along here (independent work, hides under scatter latency).
__global__ void expand_kernel(const int* __restrict__ row, const int* __restrict__ col,
                              int* __restrict__ cursorA, int* __restrict__ cursorB,
                              unsigned short* __restrict__ entries,
                              const float* __restrict__ x, unsigned short* __restrict__ xb) {
    int i = blockIdx.x * blockDim.x + threadIdx.x;
    int gstride = gridDim.x * blockDim.x;
    for (int e = i; e < NEDGE; e += gstride) {
        int r = row[e], c = col[e];
        int p1 = atomicAdd(&cursorA[r], 1);
        if (p1 < CAP) entries[(size_t)r * CAP + p1] = (unsigned short)c;
        int p2 = atomicAdd(&cursorB[c], 1);
        if (p2 < CAP) entries[(size_t)c * CAP + (CAP - 1 - p2)] = (unsigned short)r;
    }
    if (xb) {
        for (int t = i; t < N_NODES * D / 4; t += gstride) {
            float4 v = ((const float4*)x)[t];
            ushort4 o;
            o.x = bf16rn(v.x); o.y = bf16rn(v.y); o.z = bf16rn(v.z); o.w = bf16rn(v.w);
            ((ushort4*)xb)[t] = o;
        }
    }
}

// Fused gather + linear (r9 shape: 4 waves/block, 2 nodes/wave, 32 lanes x 8B bf16).
// Staging: compact both segment regions into LDS ([0,a) = dir0, [a,m) = dir1),
// rev-detect by scanning the opposite region, pack {src | isRe<<16, signed s}.
// d_out written exactly once, never read. 14.7KB LDS -> 8 blocks/CU (32 waves).
template <int USE_BF16>
__global__ __launch_bounds__(256) void fused_kernel(
    const float* __restrict__ x, const unsigned short* __restrict__ xb,
    const unsigned short* __restrict__ entries,
    const int* __restrict__ cursorA, const int* __restrict__ cursorB,
    const float* __restrict__ Wc, const float* __restrict__ bc,
    float* __restrict__ out) {
    __shared__ unsigned short rawlds[4][2][CAP];  // 1280 B : src ids, compacted
    __shared__ uint2 slds[4][2][CAP];             // 5120 B : src|isRe<<16, signed s
    __shared__ float ylds[8][260];                // 8320 B, padded stride

    int tid = threadIdx.x;
    int wave = tid >> 6, half = (tid >> 5) & 1, l = tid & 31;
    int n = wave * 2 + half;
    int u = blockIdx.x * 8 + n;

    int cA = cursorA[u], cB = cursorB[u];
    int a = min(cA, CAP);
    int b = min(cB, CAP - a);
    int m = a + b;
    int cnt = cA + cB;
    float dinv_u = (cnt > 0) ? rsqrtf(0.5f * (float)cnt) : 0.f;
    const unsigned short* eb = entries + (size_t)u * CAP;
    int gap = CAP - m;

    // Stage both regions, compacted: [0,a) from bottom, [a,m) from top region.
    for (int t = l; t < m; t += 32)
        rawlds[wave][half][t] = eb[t < a ? t : t + gap];
    __builtin_amdgcn_wave_barrier();

    // Rev-detect (scan opposite region) + scale + pack.
    for (int t = l; t < m; t += 32) {
        unsigned short src = rawlds[wave][half][t];
        bool d1 = (t >= a);
        int lo = d1 ? 0 : a, hi = d1 ? a : m;
        bool rev = false;
        for (int j = lo; j < hi; ++j)
            rev |= (rawlds[wave][half][j] == src);
        int cs = cursorA[src] + cursorB[src];
        float s = 0.5f * dinv_u * rsqrtf(0.5f * (float)max(cs, 1));
        unsigned flag = 0u;
        float sval;
        if (rev) { sval = s; flag = 0x10000u; }       // real part
        else     { sval = d1 ? -s : s; }              // imag part, sign by direction
        slds[wave][half][t] = make_uint2((unsigned)src | flag, __float_as_uint(sval));
    }
    __builtin_amdgcn_wave_barrier();

    float4 accre = make_float4(0.f, 0.f, 0.f, 0.f);
    float4 accim = make_float4(0.f, 0.f, 0.f, 0.f);

    if (USE_BF16) {
        #pragma unroll 8
        for (int i = 0; i < m; ++i) {
            uint2 t = slds[wave][half][i];
            unsigned src = t.x & 0xFFFFu;
            float s = __uint_as_float(t.y);
            bool isre = (t.x & 0x10000u) != 0u;
            float fre = isre ? s : 0.f;
            float fim = isre ? 0.f : s;
            uint2 v = ((const uint2*)(xb + (size_t)src * D))[l];
            float v0 = __uint_as_float(v.x << 16);
            float v1 = __uint_as_float(v.x & 0xFFFF0000u);
            float v2 = __uint_as_float(v.y << 16);
            float v3 = __uint_as_float(v.y & 0xFFFF0000u);
            accre.x += fre * v0; accre.y += fre * v1;
            accre.z += fre * v2; accre.w += fre * v3;
            accim.x += fim * v0; accim.y += fim * v1;
            accim.z += fim * v2; accim.w += fim * v3;
        }
    } else {
        #pragma unroll 4
        for (int i = 0; i < m; ++i) {
            uint2 t = slds[wave][half][i];
            unsigned src = t.x & 0xFFFFu;
            float s = __uint_as_float(t.y);
            bool isre = (t.x & 0x10000u) != 0u;
            float fre = isre ? s : 0.f;
            float fim = isre ? 0.f : s;
            float4 v = ((const float4*)(x + (size_t)src * D))[l];
            accre.x += fre * v.x; accre.y += fre * v.y;
            accre.z += fre * v.z; accre.w += fre * v.w;
            accim.x += fim * v.x; accim.y += fim * v.y;
            accim.z += fim * v.z; accim.w += fim * v.w;
        }
    }

    *(float4*)&ylds[n][l * 4] = accre;
    *(float4*)&ylds[n][128 + l * 4] = accim;
    __syncthreads();

    // Linear: thread = (node n2, col-quad c). out[u2] = y[u2] @ Wc + bc, both halves.
    int n2 = tid >> 5, c = tid & 31;
    int u2 = blockIdx.x * 8 + n2;
    const float* yb = &ylds[n2][0];
    const float4* Wc4 = (const float4*)Wc;
    float4 ar = make_float4(0.f, 0.f, 0.f, 0.f);
    float4 ai = make_float4(0.f, 0.f, 0.f, 0.f);
    #pragma unroll 4
    for (int k = 0; k < 128; k += 4) {
        float4 yr4 = *(const float4*)&yb[k];
        float4 yi4 = *(const float4*)&yb[128 + k];
        #pragma unroll
        for (int j = 0; j < 4; ++j) {
            float4 w = Wc4[(k + j) * 32 + c];
            float yr = (j == 0) ? yr4.x : (j == 1) ? yr4.y : (j == 2) ? yr4.z : yr4.w;
            float yi = (j == 0) ? yi4.x : (j == 1) ? yi4.y : (j == 2) ? yi4.z : yi4.w;
            ar.x += yr * w.x; ar.y += yr * w.y; ar.z += yr * w.z; ar.w += yr * w.w;
            ai.x += yi * w.x; ai.y += yi * w.y; ai.z += yi * w.z; ai.w += yi * w.w;
        }
    }
    float4 bv = ((const float4*)bc)[c];
    ar.x += bv.x; ar.y += bv.y; ar.z += bv.z; ar.w += bv.w;
    ai.x += bv.x; ai.y += bv.y; ai.z += bv.z; ai.w += bv.w;
    *(float4*)&out[(size_t)u2 * 256 + c * 4] = ar;
    *(float4*)&out[(size_t)u2 * 256 + 128 + c * 4] = ai;
}

extern "C" void kernel_launch(void* const* d_in, const int* in_sizes, int n_in,
                              void* d_out, int out_size, void* d_ws, size_t ws_size,
                              hipStream_t stream) {
    const float* x  = (const float*)d_in[0];
    const int*   ei = (const int*)d_in[1];
    const float* W1 = (const float*)d_in[2];
    const float* b1 = (const float*)d_in[3];
    const float* W2 = (const float*)d_in[4];
    const float* b2 = (const float*)d_in[5];
    float* out = (float*)d_out;
    const int* row = ei;
    const int* col = ei + NEDGE;

    char* ws = (char*)d_ws;
    float*          Wc      = (float*)ws;                 // 0        .. 65536
    float*          bc      = (float*)(ws + 65536);       // 65536    .. 66048
    int*            cursorA = (int*)(ws + 66048);         // 66048    .. 226048
    int*            cursorB = (int*)(ws + 226048);        // 226048   .. 386048
    unsigned short* entries = (unsigned short*)(ws + 386048);  // 386048 .. 6786048 (N*CAP*2)
    const size_t xoff = 6786048;                          // 16B-aligned
    const size_t XBB = (size_t)N_NODES * D * 2;           // 10.24 MB

    unsigned short* xb = nullptr;
    bool bf16 = false;
    if (ws_size >= xoff + XBB) {
        xb = (unsigned short*)(ws + xoff);
        bf16 = true;
    }

    init_kernel<<<512, 256, 0, stream>>>(cursorA, cursorB, W1, b1, W2, b2, Wc, bc);
    expand_kernel<<<2500, 256, 0, stream>>>(row, col, cursorA, cursorB, entries, x, xb);
    if (bf16) {
        fused_kernel<1><<<N_NODES / 8, 256, 0, stream>>>(x, xb, entries, cursorA, cursorB,
                                                         Wc, bc, out);
    } else {
        fused_kernel<0><<<N_NODES / 8, 256, 0, stream>>>(x, xb, entries, cursorA, cursorB,
                                                         Wc, bc, out);
    }
}